// Round 3
// baseline (93.322 us; speedup 1.0000x reference)
//
#include <hip/hip_runtime.h>
#include <hip/hip_bf16.h>

#define F_DIM 512
#define NT 512
#define DEPTH 5
#define NCOL (NT * DEPTH)   // 2560
#define BATCH 2048

typedef __attribute__((ext_vector_type(8))) short bf16x8;
typedef __attribute__((ext_vector_type(4))) float f32x4;

__device__ __forceinline__ void gl2lds16(const void* g, void* l) {
    __builtin_amdgcn_global_load_lds((const __attribute__((address_space(1))) void*)g,
                                     (__attribute__((address_space(3))) void*)l,
                                     16, 0, 0);
}

// ---------------------------------------------------------------------------
// Kernel 1: prep = cast_x (blocks 0..1023) + column-softmax->Wt (blocks 1024..1183)
// ---------------------------------------------------------------------------
__global__ __launch_bounds__(256) void prep(const float* __restrict__ x,
                                            const float* __restrict__ fa,
                                            __hip_bfloat16* __restrict__ Xb,
                                            __hip_bfloat16* __restrict__ Wt) {
    if (blockIdx.x < 1024) {
        const size_t i = (size_t)blockIdx.x * 256 + threadIdx.x;
        const float4 v = ((const float4*)x)[i];
        union { ushort4 u; __hip_bfloat16 h[4]; } pk;
        pk.h[0] = __float2bfloat16(v.x);
        pk.h[1] = __float2bfloat16(v.y);
        pk.h[2] = __float2bfloat16(v.z);
        pk.h[3] = __float2bfloat16(v.w);
        ((ushort4*)Xb)[i] = pk.u;
        return;
    }
    const int bx = blockIdx.x - 1024;        // 0..159
    const int l = threadIdx.x & 15;
    const int g = threadIdx.x >> 4;
    const int col = bx * 16 + l;
    const int f0 = g * 32;
    __shared__ float red[16][16];

    float e[32];
    float s = 0.f;
#pragma unroll
    for (int i = 0; i < 32; ++i) {
        e[i] = __expf(fa[(size_t)(f0 + i) * NCOL + col]);
        s += e[i];
    }
    red[g][l] = s;
    __syncthreads();

    float S = 0.f;
#pragma unroll
    for (int gg = 0; gg < 16; ++gg) S += red[gg][l];
    const float inv = 1.0f / S;

    __hip_bfloat16* dst = Wt + (size_t)col * F_DIM + f0;
#pragma unroll
    for (int i = 0; i < 32; i += 4) {
        union { ushort4 u; __hip_bfloat16 h[4]; } pk;
#pragma unroll
        for (int jj = 0; jj < 4; ++jj)
            pk.h[jj] = __float2bfloat16(e[i + jj] * inv);
        *(ushort4*)(dst + i) = pk.u;
    }
}

// ---------------------------------------------------------------------------
// Kernel 2: fused GEMM + tree routing, v2.
//  - A (Xb) fragments loaded DIRECTLY global->VGPR (coalesced 16 rows x 64B
//    per instr, L1/L2-resident) — no As staging, LDS reads are B-only.
//  - B staged via global_load_lds into DOUBLE-BUFFERED Bs (2 x 160x64 bf16):
//    one barrier per stage; next stage's loads issued right after the barrier
//    so the compiler's vmcnt(0)-before-barrier drains loads issued a full
//    compute-stage earlier (true prefetch overlap at 1 block/CU).
//  - Epilogue (tree DP-fold) unchanged from R2; E slab reuses Bs LDS.
// ---------------------------------------------------------------------------
__global__ __launch_bounds__(256, 1) void gemm_tree(const __hip_bfloat16* __restrict__ A,
                                                    const __hip_bfloat16* __restrict__ Bt,
                                                    const float* __restrict__ th,
                                                    const float* __restrict__ lt,
                                                    const float* __restrict__ resp,
                                                    float* __restrict__ out) {
    __shared__ __align__(16) char smem[40960];   // Bs dbuf 2x20KB; E slab (20.6KB) reuses
    __hip_bfloat16* Bs0 = (__hip_bfloat16*)smem;           // [160][64]
    __hip_bfloat16* Bs1 = (__hip_bfloat16*)(smem + 20480); // [160][64]
    float* E = (float*)smem;                               // [32][161]

    const int tid = threadIdx.x;
    const int w = tid >> 6;
    const int l = tid & 63;
    const int m0 = blockIdx.y * 128;      // batch-row base
    const int n0c = blockIdx.x * 160;     // fv-column base
    const int n0t = blockIdx.x * 32;      // tree base
    const int wm = (w & 1) * 64;
    const int wn = (w >> 1) * 80;

    f32x4 acc[4][5] = {};

    const int srow = l >> 3;              // row within 8-row staging group
    const int schunk = (l & 7) ^ srow;    // xor-swizzled source chunk

    // stage B tile for k-chunk st into buffer buf
    auto stageB = [&](int st, __hip_bfloat16* buf) {
        const int k0 = st * 64;
#pragma unroll
        for (int q = 0; q < 5; ++q) {     // 20 groups of 8 rows, 4 waves
            const int g = q * 4 + w;
            gl2lds16(Bt + ((size_t)(n0c + g * 8 + srow) * F_DIM + k0 + schunk * 8),
                     buf + g * 8 * 64);
        }
    };

    stageB(0, Bs0);

    for (int st = 0; st < 8; ++st) {
        __hip_bfloat16* cur = (st & 1) ? Bs1 : Bs0;
        __hip_bfloat16* nxt = (st & 1) ? Bs0 : Bs1;
        __syncthreads();                  // drains B(st) (issued one stage ago)
        if (st < 7) stageB(st + 1, nxt);  // prefetch; drained at NEXT barrier

        const int k0 = st * 64;
        // A fragments for this stage: 8 x 16B direct global loads
        bf16x8 af[2][4];
#pragma unroll
        for (int ks = 0; ks < 2; ++ks) {
            const int cb = ks * 4 + (l >> 4);
#pragma unroll
            for (int im = 0; im < 4; ++im)
                af[ks][im] = *(const bf16x8*)(
                    A + (size_t)(m0 + wm + im * 16 + (l & 15)) * F_DIM + k0 + cb * 8);
        }
#pragma unroll
        for (int ks = 0; ks < 2; ++ks) {
            const int cb = ks * 4 + (l >> 4);
            bf16x8 bfr[5];
#pragma unroll
            for (int in = 0; in < 5; ++in) {
                const int r = wn + in * 16 + (l & 15);
                bfr[in] = *(const bf16x8*)(cur + r * 64 + ((cb ^ (r & 7)) * 8));
            }
#pragma unroll
            for (int im = 0; im < 4; ++im)
#pragma unroll
                for (int in = 0; in < 5; ++in)
                    acc[im][in] = __builtin_amdgcn_mfma_f32_16x16x32_bf16(
                        af[ks][im], bfr[in], acc[im][in], 0, 0, 0);
        }
    }
    __syncthreads();   // all Bs reads done before E slab overwrites LDS

    // ---- tree epilogue (as R2) ----
    const int tree = tid & 31;
    const int rg = tid >> 5;
    const int gt = n0t + tree;

    float al[DEPTH], be[DEPTH];
#pragma unroll
    for (int j = 0; j < DEPTH; ++j) {
        const float a = 0.5f * __expf(-lt[gt * DEPTH + j]);
        al[j] = a;
        be[j] = 0.5f - th[gt * DEPTH + j] * a;
    }
    float rs[32];
#pragma unroll
    for (int i = 0; i < 32; ++i) rs[i] = resp[gt * 32 + i];

    const int PAD = 161;
#pragma unroll
    for (int im = 0; im < 4; ++im) {
#pragma unroll
        for (int in = 0; in < 5; ++in) {
            const int scol = wn + in * 16 + (l & 15);
#pragma unroll
            for (int r = 0; r < 4; ++r) {
                const int sr = (w & 1) * 16 + (l >> 4) * 4 + r;
                E[sr * PAD + scol] = acc[im][in][r];
            }
        }
        __syncthreads();

#pragma unroll
        for (int rr = 0; rr < 4; ++rr) {
            const int s = rg * 4 + rr;
            const int gb = m0 + ((s < 16) ? (im * 16 + s) : (64 + im * 16 + (s - 16)));
            const float* f = E + s * PAD + tree * 5;
            float c1[DEPTH];
#pragma unroll
            for (int j = 0; j < DEPTH; ++j) {
                const float v = fmaf(al[j], f[j], be[j]);
                c1[j] = fminf(fmaxf(v, 0.f), 1.f);
            }
            float s16[16], s8[8], s4[4], s2[2];
#pragma unroll
            for (int m = 0; m < 16; ++m) s16[m] = fmaf(c1[0], rs[2*m+1] - rs[2*m], rs[2*m]);
#pragma unroll
            for (int m = 0; m < 8; ++m)  s8[m]  = fmaf(c1[1], s16[2*m+1] - s16[2*m], s16[2*m]);
#pragma unroll
            for (int m = 0; m < 4; ++m)  s4[m]  = fmaf(c1[2], s8[2*m+1] - s8[2*m], s8[2*m]);
#pragma unroll
            for (int m = 0; m < 2; ++m)  s2[m]  = fmaf(c1[3], s4[2*m+1] - s4[2*m], s4[2*m]);
            out[(size_t)gb * NT + gt] = fmaf(c1[4], s2[1] - s2[0], s2[0]);
        }
        __syncthreads();
    }
}

// ---------------------------------------------------------------------------
extern "C" void kernel_launch(void* const* d_in, const int* in_sizes, int n_in,
                              void* d_out, int out_size, void* d_ws, size_t ws_size,
                              hipStream_t stream) {
    const float* x    = (const float*)d_in[0];
    const float* fa   = (const float*)d_in[1];
    const float* th   = (const float*)d_in[2];
    const float* lt   = (const float*)d_in[3];
    const float* resp = (const float*)d_in[4];
    // d_in[5] = path_map: deterministic oblivious layout, hardcoded in epilogue.

    char* ws = (char*)d_ws;
    __hip_bfloat16* Wt = (__hip_bfloat16*)(ws);                 // 2560*512*2 = 2.62 MB
    __hip_bfloat16* Xb = (__hip_bfloat16*)(ws + (4u << 20));    // 2048*512*2 = 2.10 MB
    float* out = (float*)d_out;

    hipLaunchKernelGGL(prep, dim3(1024 + 160), dim3(256), 0, stream, x, fa, Xb, Wt);
    hipLaunchKernelGGL(gemm_tree, dim3(NCOL / 160, BATCH / 128), dim3(256), 0, stream,
                       Xb, Wt, th, lt, resp, out);
}

// Round 4
// 90.231 us; speedup vs baseline: 1.0343x; 1.0343x over previous
//
#include <hip/hip_runtime.h>
#include <hip/hip_bf16.h>

#define F_DIM 512
#define NT 512
#define DEPTH 5
#define NCOL (NT * DEPTH)   // 2560
#define BATCH 2048

typedef __attribute__((ext_vector_type(8))) short bf16x8;
typedef __attribute__((ext_vector_type(4))) float f32x4;

__device__ __forceinline__ void gl2lds16(const void* g, void* l) {
    __builtin_amdgcn_global_load_lds((const __attribute__((address_space(1))) void*)g,
                                     (__attribute__((address_space(3))) void*)l,
                                     16, 0, 0);
}

// ---------------------------------------------------------------------------
// Kernel 1: prep = cast_x (blocks 0..1023) + column-softmax->Wt (blocks 1024..1183)
// ---------------------------------------------------------------------------
__global__ __launch_bounds__(256) void prep(const float* __restrict__ x,
                                            const float* __restrict__ fa,
                                            __hip_bfloat16* __restrict__ Xb,
                                            __hip_bfloat16* __restrict__ Wt) {
    if (blockIdx.x < 1024) {
        const size_t i = (size_t)blockIdx.x * 256 + threadIdx.x;
        const float4 v = ((const float4*)x)[i];
        union { ushort4 u; __hip_bfloat16 h[4]; } pk;
        pk.h[0] = __float2bfloat16(v.x);
        pk.h[1] = __float2bfloat16(v.y);
        pk.h[2] = __float2bfloat16(v.z);
        pk.h[3] = __float2bfloat16(v.w);
        ((ushort4*)Xb)[i] = pk.u;
        return;
    }
    const int bx = blockIdx.x - 1024;        // 0..159
    const int l = threadIdx.x & 15;
    const int g = threadIdx.x >> 4;
    const int col = bx * 16 + l;
    const int f0 = g * 32;
    __shared__ float red[16][16];

    float e[32];
    float s = 0.f;
#pragma unroll
    for (int i = 0; i < 32; ++i) {
        e[i] = __expf(fa[(size_t)(f0 + i) * NCOL + col]);
        s += e[i];
    }
    red[g][l] = s;
    __syncthreads();

    float S = 0.f;
#pragma unroll
    for (int gg = 0; gg < 16; ++gg) S += red[gg][l];
    const float inv = 1.0f / S;

    __hip_bfloat16* dst = Wt + (size_t)col * F_DIM + f0;
#pragma unroll
    for (int i = 0; i < 32; i += 4) {
        union { ushort4 u; __hip_bfloat16 h[4]; } pk;
#pragma unroll
        for (int jj = 0; jj < 4; ++jj)
            pk.h[jj] = __float2bfloat16(e[i + jj] * inv);
        *(ushort4*)(dst + i) = pk.u;
    }
}

// ---------------------------------------------------------------------------
// Kernel 2: fused GEMM + tree routing, v3 (R3 bug fixed).
// Pipeline per stage st:
//   barrier  -- drains A(st)+B(st), both issued one FULL compute stage ago
//   issue A(st+1) (direct global->VGPR, BEFORE the LDS prefetch so any wait
//                  on it never forces draining the B queue)
//   issue B(st+1) (global_load_lds -> other Bs buffer)
//   compute(st)   -- af from regs, B frags from LDS: zero vmem waits
// This hides the ~200-900 cyc load latency behind ~900 cyc of MFMA+ds_read.
// ---------------------------------------------------------------------------
__global__ __launch_bounds__(256, 1) void gemm_tree(const __hip_bfloat16* __restrict__ A,
                                                    const __hip_bfloat16* __restrict__ Bt,
                                                    const float* __restrict__ th,
                                                    const float* __restrict__ lt,
                                                    const float* __restrict__ resp,
                                                    float* __restrict__ out) {
    __shared__ __align__(16) char smem[40960];   // Bs dbuf 2x20KB; E slab (20.6KB) reuses
    __hip_bfloat16* Bs0 = (__hip_bfloat16*)smem;           // [160][64]
    __hip_bfloat16* Bs1 = (__hip_bfloat16*)(smem + 20480); // [160][64]
    float* E = (float*)smem;                               // [32][161]

    const int tid = threadIdx.x;
    const int w = tid >> 6;
    const int l = tid & 63;
    const int m0 = blockIdx.y * 128;      // batch-row base
    const int n0c = blockIdx.x * 160;     // fv-column base
    const int n0t = blockIdx.x * 32;      // tree base
    const int wm = (w & 1) * 64;
    const int wn = (w >> 1) * 80;

    f32x4 acc[4][5] = {};

    const int srow = l >> 3;              // row within 8-row staging group
    const int schunk = (l & 7) ^ srow;    // xor-swizzled source chunk

    auto stageB = [&](int st, __hip_bfloat16* buf) {
        const int k0 = st * 64;
#pragma unroll
        for (int q = 0; q < 5; ++q) {     // 20 groups of 8 rows, 4 waves
            const int g = q * 4 + w;
            gl2lds16(Bt + ((size_t)(n0c + g * 8 + srow) * F_DIM + k0 + schunk * 8),
                     buf + g * 8 * 64);
        }
    };

    bf16x8 af[2][2][4];                   // [stage parity][ks][im]
    auto loadA = [&](int st, bf16x8 dst[2][4]) {
        const int k0 = st * 64;
#pragma unroll
        for (int ks = 0; ks < 2; ++ks) {
            const int cb = ks * 4 + (l >> 4);
#pragma unroll
            for (int im = 0; im < 4; ++im)
                dst[ks][im] = *(const bf16x8*)(
                    A + (size_t)(m0 + wm + im * 16 + (l & 15)) * F_DIM + k0 + cb * 8);
        }
    };

    loadA(0, af[0]);                      // A first, then B: A never blocks the B queue
    stageB(0, Bs0);

#pragma unroll
    for (int st = 0; st < 8; ++st) {
        __hip_bfloat16* cur = (st & 1) ? Bs1 : Bs0;
        __hip_bfloat16* nxt = (st & 1) ? Bs0 : Bs1;
        __syncthreads();                  // drains stage-st loads (issued one stage ago)
        if (st < 7) {
            loadA(st + 1, af[(st + 1) & 1]);
            stageB(st + 1, nxt);
        }
#pragma unroll
        for (int ks = 0; ks < 2; ++ks) {
            const int cb = ks * 4 + (l >> 4);
            bf16x8 bfr[5];
#pragma unroll
            for (int in = 0; in < 5; ++in) {
                const int r = wn + in * 16 + (l & 15);
                bfr[in] = *(const bf16x8*)(cur + r * 64 + ((cb ^ (r & 7)) * 8));
            }
#pragma unroll
            for (int im = 0; im < 4; ++im)
#pragma unroll
                for (int in = 0; in < 5; ++in)
                    acc[im][in] = __builtin_amdgcn_mfma_f32_16x16x32_bf16(
                        af[st & 1][ks][im], bfr[in], acc[im][in], 0, 0, 0);
        }
    }
    __syncthreads();   // all Bs reads done before E slab overwrites LDS

    // ---- tree epilogue ----
    const int tree = tid & 31;
    const int rg = tid >> 5;
    const int gt = n0t + tree;

    float al[DEPTH], be[DEPTH];
#pragma unroll
    for (int j = 0; j < DEPTH; ++j) {
        const float a = 0.5f * __expf(-lt[gt * DEPTH + j]);
        al[j] = a;
        be[j] = 0.5f - th[gt * DEPTH + j] * a;
    }
    float rs[32];
#pragma unroll
    for (int i = 0; i < 32; ++i) rs[i] = resp[gt * 32 + i];

    const int PAD = 161;
#pragma unroll
    for (int im = 0; im < 4; ++im) {
#pragma unroll
        for (int in = 0; in < 5; ++in) {
            const int scol = wn + in * 16 + (l & 15);
#pragma unroll
            for (int r = 0; r < 4; ++r) {
                const int sr = (w & 1) * 16 + (l >> 4) * 4 + r;
                E[sr * PAD + scol] = acc[im][in][r];
            }
        }
        __syncthreads();

#pragma unroll
        for (int rr = 0; rr < 4; ++rr) {
            const int s = rg * 4 + rr;
            const int gb = m0 + ((s < 16) ? (im * 16 + s) : (64 + im * 16 + (s - 16)));
            const float* f = E + s * PAD + tree * 5;
            float c1[DEPTH];
#pragma unroll
            for (int j = 0; j < DEPTH; ++j) {
                const float v = fmaf(al[j], f[j], be[j]);
                c1[j] = fminf(fmaxf(v, 0.f), 1.f);
            }
            float s16[16], s8[8], s4[4], s2[2];
#pragma unroll
            for (int m = 0; m < 16; ++m) s16[m] = fmaf(c1[0], rs[2*m+1] - rs[2*m], rs[2*m]);
#pragma unroll
            for (int m = 0; m < 8; ++m)  s8[m]  = fmaf(c1[1], s16[2*m+1] - s16[2*m], s16[2*m]);
#pragma unroll
            for (int m = 0; m < 4; ++m)  s4[m]  = fmaf(c1[2], s8[2*m+1] - s8[2*m], s8[2*m]);
#pragma unroll
            for (int m = 0; m < 2; ++m)  s2[m]  = fmaf(c1[3], s4[2*m+1] - s4[2*m], s4[2*m]);
            out[(size_t)gb * NT + gt] = fmaf(c1[4], s2[1] - s2[0], s2[0]);
        }
        __syncthreads();
    }
}

// ---------------------------------------------------------------------------
extern "C" void kernel_launch(void* const* d_in, const int* in_sizes, int n_in,
                              void* d_out, int out_size, void* d_ws, size_t ws_size,
                              hipStream_t stream) {
    const float* x    = (const float*)d_in[0];
    const float* fa   = (const float*)d_in[1];
    const float* th   = (const float*)d_in[2];
    const float* lt   = (const float*)d_in[3];
    const float* resp = (const float*)d_in[4];
    // d_in[5] = path_map: deterministic oblivious layout, hardcoded in epilogue.

    char* ws = (char*)d_ws;
    __hip_bfloat16* Wt = (__hip_bfloat16*)(ws);                 // 2560*512*2 = 2.62 MB
    __hip_bfloat16* Xb = (__hip_bfloat16*)(ws + (4u << 20));    // 2048*512*2 = 2.10 MB
    float* out = (float*)d_out;

    hipLaunchKernelGGL(prep, dim3(1024 + 160), dim3(256), 0, stream, x, fa, Xb, Wt);
    hipLaunchKernelGGL(gemm_tree, dim3(NCOL / 160, BATCH / 128), dim3(256), 0, stream,
                       Xb, Wt, th, lt, resp, out);
}

// Round 5
// 83.579 us; speedup vs baseline: 1.1166x; 1.0796x over previous
//
#include <hip/hip_runtime.h>
#include <hip/hip_bf16.h>

#define F_DIM 512
#define NT 512
#define DEPTH 5
#define NCOL (NT * DEPTH)   // 2560
#define BATCH 2048

typedef __attribute__((ext_vector_type(8))) short bf16x8;
typedef __attribute__((ext_vector_type(4))) float f32x4;

__device__ __forceinline__ void gl2lds16(const void* g, void* l) {
    __builtin_amdgcn_global_load_lds((const __attribute__((address_space(1))) void*)g,
                                     (__attribute__((address_space(3))) void*)l,
                                     16, 0, 0);
}

// ---------------------------------------------------------------------------
// Kernel 1: prep = cast_x (blocks 0..1023) + column-softmax->Wt (blocks 1024..1183)
// ---------------------------------------------------------------------------
__global__ __launch_bounds__(256) void prep(const float* __restrict__ x,
                                            const float* __restrict__ fa,
                                            __hip_bfloat16* __restrict__ Xb,
                                            __hip_bfloat16* __restrict__ Wt) {
    if (blockIdx.x < 1024) {
        const size_t i = (size_t)blockIdx.x * 256 + threadIdx.x;
        const float4 v = ((const float4*)x)[i];
        union { ushort4 u; __hip_bfloat16 h[4]; } pk;
        pk.h[0] = __float2bfloat16(v.x);
        pk.h[1] = __float2bfloat16(v.y);
        pk.h[2] = __float2bfloat16(v.z);
        pk.h[3] = __float2bfloat16(v.w);
        ((ushort4*)Xb)[i] = pk.u;
        return;
    }
    const int bx = blockIdx.x - 1024;        // 0..159
    const int l = threadIdx.x & 15;
    const int g = threadIdx.x >> 4;
    const int col = bx * 16 + l;
    const int f0 = g * 32;
    __shared__ float red[16][16];

    float e[32];
    float s = 0.f;
#pragma unroll
    for (int i = 0; i < 32; ++i) {
        e[i] = __expf(fa[(size_t)(f0 + i) * NCOL + col]);
        s += e[i];
    }
    red[g][l] = s;
    __syncthreads();

    float S = 0.f;
#pragma unroll
    for (int gg = 0; gg < 16; ++gg) S += red[gg][l];
    const float inv = 1.0f / S;

    __hip_bfloat16* dst = Wt + (size_t)col * F_DIM + f0;
#pragma unroll
    for (int i = 0; i < 32; i += 4) {
        union { ushort4 u; __hip_bfloat16 h[4]; } pk;
#pragma unroll
        for (int jj = 0; jj < 4; ++jj)
            pk.h[jj] = __float2bfloat16(e[i + jj] * inv);
        *(ushort4*)(dst + i) = pk.u;
    }
}

// ---------------------------------------------------------------------------
// Kernel 2: fused GEMM + tree routing, v4.
// Tile 64 rows x 160 cols (32 whole trees); grid 16x32 = 512 blocks
//   => 2 blocks/CU resident (LDS 28KB, ~100 VGPR): the co-resident block's
//   MFMA/LDS work covers this block's barrier drains (m114 implicit overlap)
//   — the TLP that the previous 1-block/CU configs lacked.
// 4 waves in 2x2: wave = 32 rows x 80 cols = 2x5 MFMA tiles of 16x16x32.
// R2-proven two-barrier staging: global_load_lds width-16, xor chunk swizzle.
// Epilogue: 2 passes of 32 rows x 160 cols through LDS slab, DP tree fold.
// ---------------------------------------------------------------------------
__global__ __launch_bounds__(256, 2) void gemm_tree(const __hip_bfloat16* __restrict__ A,
                                                    const __hip_bfloat16* __restrict__ Bt,
                                                    const float* __restrict__ th,
                                                    const float* __restrict__ lt,
                                                    const float* __restrict__ resp,
                                                    float* __restrict__ out) {
    __shared__ __align__(16) char smem[28672];   // As 8KB + Bs 20KB; E slab (20.6KB) reuses
    __hip_bfloat16* As = (__hip_bfloat16*)smem;            // [64][64]
    __hip_bfloat16* Bs = (__hip_bfloat16*)(smem + 8192);   // [160][64]
    float* E = (float*)smem;                               // [32][161]

    const int tid = threadIdx.x;
    const int w = tid >> 6;
    const int l = tid & 63;
    const int m0 = blockIdx.y * 64;       // batch-row base
    const int n0c = blockIdx.x * 160;     // fv-column base
    const int n0t = blockIdx.x * 32;      // tree base
    const int wm = (w & 1) * 32;
    const int wn = (w >> 1) * 80;

    f32x4 acc[2][5] = {};

    const int srow = l >> 3;              // row within 8-row staging group
    const int schunk = (l & 7) ^ srow;    // xor-swizzled source chunk

    for (int kt = 0; kt < 8; ++kt) {
        const int k0 = kt * 64;
#pragma unroll
        for (int q = 0; q < 2; ++q) {     // As: 8 groups of 8 rows
            const int g = q * 4 + w;
            gl2lds16(A + ((size_t)(m0 + g * 8 + srow) * F_DIM + k0 + schunk * 8),
                     As + g * 8 * 64);
        }
#pragma unroll
        for (int q = 0; q < 5; ++q) {     // Bs: 20 groups of 8 rows
            const int g = q * 4 + w;
            gl2lds16(Bt + ((size_t)(n0c + g * 8 + srow) * F_DIM + k0 + schunk * 8),
                     Bs + g * 8 * 64);
        }
        __syncthreads();

#pragma unroll
        for (int ks = 0; ks < 2; ++ks) {
            const int cb = ks * 4 + (l >> 4);
            bf16x8 af[2], bfr[5];
#pragma unroll
            for (int im = 0; im < 2; ++im) {
                const int r = wm + im * 16 + (l & 15);
                af[im] = *(const bf16x8*)(As + r * 64 + ((cb ^ (r & 7)) * 8));
            }
#pragma unroll
            for (int in = 0; in < 5; ++in) {
                const int r = wn + in * 16 + (l & 15);
                bfr[in] = *(const bf16x8*)(Bs + r * 64 + ((cb ^ (r & 7)) * 8));
            }
#pragma unroll
            for (int im = 0; im < 2; ++im)
#pragma unroll
                for (int in = 0; in < 5; ++in)
                    acc[im][in] = __builtin_amdgcn_mfma_f32_16x16x32_bf16(
                        af[im], bfr[in], acc[im][in], 0, 0, 0);
        }
        __syncthreads();
    }

    // ---- tree epilogue ----
    const int tree = tid & 31;            // local tree 0..31
    const int rg = tid >> 5;              // row-group 0..7 (4 slab rows each)
    const int gt = n0t + tree;

    float al[DEPTH], be[DEPTH];
#pragma unroll
    for (int j = 0; j < DEPTH; ++j) {
        const float a = 0.5f * __expf(-lt[gt * DEPTH + j]);
        al[j] = a;
        be[j] = 0.5f - th[gt * DEPTH + j] * a;
    }
    float rs[32];
#pragma unroll
    for (int i = 0; i < 32; ++i) rs[i] = resp[gt * 32 + i];

    const int PAD = 161;
#pragma unroll
    for (int im = 0; im < 2; ++im) {
        // stage this im-pass's 32 rows x 160 cols to LDS:
        // w even -> slab rows 0..15 (global rows m0+im*16+s),
        // w odd  -> slab rows 16..31 (global rows m0+32+im*16+(s-16))
#pragma unroll
        for (int in = 0; in < 5; ++in) {
            const int scol = wn + in * 16 + (l & 15);
#pragma unroll
            for (int r = 0; r < 4; ++r) {
                const int sr = (w & 1) * 16 + (l >> 4) * 4 + r;
                E[sr * PAD + scol] = acc[im][in][r];
            }
        }
        __syncthreads();

#pragma unroll
        for (int rr = 0; rr < 4; ++rr) {
            const int s = rg * 4 + rr;                       // slab row 0..31
            const int gb = m0 + ((s < 16) ? (im * 16 + s) : (32 + im * 16 + (s - 16)));
            const float* f = E + s * PAD + tree * 5;
            float c1[DEPTH];
#pragma unroll
            for (int j = 0; j < DEPTH; ++j) {
                const float v = fmaf(al[j], f[j], be[j]);
                c1[j] = fminf(fmaxf(v, 0.f), 1.f);
            }
            float s16[16], s8[8], s4[4], s2[2];
#pragma unroll
            for (int m = 0; m < 16; ++m) s16[m] = fmaf(c1[0], rs[2*m+1] - rs[2*m], rs[2*m]);
#pragma unroll
            for (int m = 0; m < 8; ++m)  s8[m]  = fmaf(c1[1], s16[2*m+1] - s16[2*m], s16[2*m]);
#pragma unroll
            for (int m = 0; m < 4; ++m)  s4[m]  = fmaf(c1[2], s8[2*m+1] - s8[2*m], s8[2*m]);
#pragma unroll
            for (int m = 0; m < 2; ++m)  s2[m]  = fmaf(c1[3], s4[2*m+1] - s4[2*m], s4[2*m]);
            out[(size_t)gb * NT + gt] = fmaf(c1[4], s2[1] - s2[0], s2[0]);
        }
        __syncthreads();
    }
}

// ---------------------------------------------------------------------------
extern "C" void kernel_launch(void* const* d_in, const int* in_sizes, int n_in,
                              void* d_out, int out_size, void* d_ws, size_t ws_size,
                              hipStream_t stream) {
    const float* x    = (const float*)d_in[0];
    const float* fa   = (const float*)d_in[1];
    const float* th   = (const float*)d_in[2];
    const float* lt   = (const float*)d_in[3];
    const float* resp = (const float*)d_in[4];
    // d_in[5] = path_map: deterministic oblivious layout, hardcoded in epilogue.

    char* ws = (char*)d_ws;
    __hip_bfloat16* Wt = (__hip_bfloat16*)(ws);                 // 2560*512*2 = 2.62 MB
    __hip_bfloat16* Xb = (__hip_bfloat16*)(ws + (4u << 20));    // 2048*512*2 = 2.10 MB
    float* out = (float*)d_out;

    hipLaunchKernelGGL(prep, dim3(1024 + 160), dim3(256), 0, stream, x, fa, Xb, Wt);
    hipLaunchKernelGGL(gemm_tree, dim3(NCOL / 160, BATCH / 64), dim3(256), 0, stream,
                       Xb, Wt, th, lt, resp, out);
}